// Round 1
// 1449.011 us; speedup vs baseline: 1.0135x; 1.0135x over previous
//
#include <hip/hip_runtime.h>
#include <cfloat>
#include <cmath>

// ---------------------------------------------------------------------------
// Round 18: break per-load waitcnt serialization in the decoder convT kernels.
// R17 counters: convt_mfma_v2 at 188us with MfmaUtil 7%, VALUBusy 8%, HBM 5%,
// VGPR=48 -- latency-bound, and 451k cyc/wave / 384 loads ~= 1.2k cyc/load:
// loads are serialized INDIVIDUALLY. Cause: each X load is immediately
// consumed by (u64 >> sh) inside loadStep, so the compiler (at its 48-VGPR
// pressure target) emits load->wait->shift chains. Fix:
//   (a) stage RAW u16x4 values; defer the shift/extract to the MFMA phase;
//   (b) sched_barrier(0) fences so the prefetch load block cannot be sunk
//       below the MFMA block (hipcc's known reordering failure mode).
// Same MFMA sequence per accumulator => bit-identical results.
// Applied to convt_mfma_v2 (dec2/dec3) and convt_mfma (dec1).
// ---------------------------------------------------------------------------

using f32x4  = __attribute__((ext_vector_type(4))) float;
using bf16x8 = __attribute__((ext_vector_type(8))) short;
typedef float f32x4u __attribute__((ext_vector_type(4), aligned(4)));
typedef unsigned short u16x4u __attribute__((ext_vector_type(4), aligned(4)));

__device__ __forceinline__ unsigned short f32_to_bf16(float f) {
    unsigned int u = __float_as_uint(f);
    u += 0x7fffu + ((u >> 16) & 1u);          // round-to-nearest-even
    return (unsigned short)(u >> 16);
}
__device__ __forceinline__ void split_bf16(float v, unsigned short& h, unsigned short& l) {
    h = f32_to_bf16(v);
    float hf = __uint_as_float((unsigned)h << 16);
    l = f32_to_bf16(v - hf);
}
__device__ __forceinline__ void store_act(float* p, float v) { *p = v; }
__device__ __forceinline__ void store_act(unsigned short* p, float v) { *p = f32_to_bf16(v); }

template <typename V>
__device__ __forceinline__ bf16x8 pack_b(V r0, V r1) {
    bf16x8 b;
    b[0] = (short)r0[0]; b[1] = (short)r0[1]; b[2] = (short)r0[2]; b[3] = (short)r0[3];
    b[4] = (short)r1[0]; b[5] = (short)r1[1]; b[6] = (short)r1[2]; b[7] = (short)r1[3];
    return b;
}

// ---------------- prep: weight hi/lo split ----------------
__global__ __launch_bounds__(256)
void prep_split_w(const float* __restrict__ w, short* __restrict__ whi,
                  short* __restrict__ wlo, long total)
{
    long idx = (long)blockIdx.x * blockDim.x + threadIdx.x;
    if (idx >= total) return;
    unsigned short h, l;
    split_bf16(w[idx], h, l);
    whi[idx] = (short)h; wlo[idx] = (short)l;
}

// ---------------- pad input -> hi/lo bf16 pitched planes --------------------
__global__ __launch_bounds__(256)
void pad_input_split(const float* __restrict__ x, unsigned short* __restrict__ xhi,
                     unsigned short* __restrict__ xlo)
{
    const int D = 64, PD = 66, PRX = 68, BC = 6;
    long total = (long)BC * PD * PD * PRX;
    long idx = (long)blockIdx.x * blockDim.x + threadIdx.x;
    if (idx >= total) return;
    int px = (int)(idx % PRX); long t = idx / PRX;
    int py = (int)(t % PD); t /= PD;
    int pz = (int)(t % PD); int c = (int)(t / PD);
    int ix = px - 1, iy = py - 1, iz = pz - 1;
    float v = 0.0f;
    if ((unsigned)ix < (unsigned)D && (unsigned)iy < (unsigned)D && (unsigned)iz < (unsigned)D)
        v = x[(((long)c * D + iz) * D + iy) * D + ix];
    unsigned short h, l;
    split_bf16(v, h, l);
    xhi[idx] = h; xlo[idx] = l;
}

__global__ __launch_bounds__(256)
void zero_halo_ps(unsigned short* __restrict__ p, int C, int PD, int PRX)
{
    long total = (long)C * PD * PD * PRX;
    long idx = (long)blockIdx.x * blockDim.x + threadIdx.x;
    if (idx >= total) return;
    int px = (int)(idx % PRX); long t = idx / PRX;
    int py = (int)(t % PD); t /= PD;
    int pz = (int)(t % PD);
    if (px == 0 || px >= PD - 1 || py == 0 || py == PD - 1 || pz == 0 || pz == PD - 1)
        p[idx] = 0;
}

template <typename T>
__global__ __launch_bounds__(256) void zero_halo_t(T* __restrict__ p, int C, int PD)
{
    long total = (long)C * PD * PD * PD;
    long idx = (long)blockIdx.x * blockDim.x + threadIdx.x;
    if (idx >= total) return;
    int px = (int)(idx % PD); long t = idx / PD;
    int py = (int)(t % PD); t /= PD;
    int pz = (int)(t % PD);
    if (px == 0 || px == PD - 1 || py == 0 || py == PD - 1 || pz == 0 || pz == PD - 1)
        p[idx] = (T)0;
}

// ---------------------------------------------------------------------------
// Conv3d k4 s2 p1 as MFMA implicit GEMM, bf16 hi/lo pair inputs (unchanged)
// ---------------------------------------------------------------------------
template <int CIN, int COUT, int DOUT, int PD, int PRX, int MTW, int OWT,
          int OWHALF, int KSPLIT, int OUTSPLIT>
__global__ __launch_bounds__(256)
void conv_s2_mfma(const unsigned short* __restrict__ xhi,
                  const unsigned short* __restrict__ xlo,
                  const short* __restrict__ Whi, const short* __restrict__ Wlo,
                  const float* __restrict__ bias,
                  unsigned short* __restrict__ yhi, unsigned short* __restrict__ ylo,
                  float* __restrict__ yf,
                  int OPD, int OPRX, int po, long sstride)
{
    constexpr int K = CIN * 64;
    constexpr int MWAVES = COUT / (16 * MTW);
    constexpr int RPB = 4 / MWAVES;
    constexpr int KN = (CIN * 2) / KSPLIT;

    int bx = blockIdx.x;
    const int ks = (KSPLIT > 1) ? (bx % KSPLIT) : 0;
    const int rowblk = (KSPLIT > 1) ? (bx / KSPLIT) : bx;
    const int lane = (int)threadIdx.x & 63, w = (int)threadIdx.x >> 6;
    const int mi = (MWAVES == 4) ? w : 0;
    const int ri = (MWAVES == 4) ? 0 : w;
    const int rowid = rowblk * RPB + ri;
    const int n16 = lane & 15, quad = lane >> 4;

    int b, od, oh, ow;
    if (OWHALF) {
        constexpr int NOH = DOUT / 2;
        const int ohb = rowid % NOH; int t = rowid / NOH;
        od = t % DOUT; b = t / DOUT;
        oh = ohb * 2 + (n16 >> 3);
        ow = n16 & 7;
    } else {
        const int owt = rowid % OWT; int t = rowid / OWT;
        oh = t % DOUT; t /= DOUT;
        od = t % DOUT; b = t / DOUT;
        ow = owt * 16 + n16;
    }

    const int co0 = mi * (MTW * 16);

    f32x4 acc[MTW];
    #pragma unroll
    for (int mt = 0; mt < MTW; ++mt)
        #pragma unroll
        for (int r = 0; r < 4; ++r) {
            int co = co0 + mt * 16 + quad * 4 + r;
            acc[mt][r] = (ks == 0) ? bias[co] : 0.0f;
        }

    const int sg0 = ks * KN;
    const long chs = (long)PD * PD * PRX;
    long off = ((long)(b * CIN + (sg0 >> 1)) * PD + (2 * od + (quad >> 1))) * PD * PRX
             + (long)(2 * oh + (quad & 1) * 2) * PRX + 2 * ow;
    const unsigned short* phi = xhi + off;
    const unsigned short* plo = xlo + off;
    const long incA = 2L * PD * PRX;
    const long incB = chs - 2L * PD * PRX;

    const short* a0h = Whi + (long)(co0 + n16) * K + sg0 * 32 + quad * 8;
    const short* a0l = Wlo + (long)(co0 + n16) * K + sg0 * 32 + quad * 8;

    #pragma unroll 2
    for (int s = 0; s < KN; ++s) {
        u16x4u h0 = *(const u16x4u*)phi;
        u16x4u h1 = *(const u16x4u*)(phi + PRX);
        u16x4u l0 = *(const u16x4u*)plo;
        u16x4u l1 = *(const u16x4u*)(plo + PRX);
        bf16x8 bhi = pack_b(h0, h1);
        bf16x8 blo = pack_b(l0, l1);
        #pragma unroll
        for (int mt = 0; mt < MTW; ++mt) {
            bf16x8 ah = *(const bf16x8*)(a0h + (long)mt * 16 * K + s * 32);
            bf16x8 al = *(const bf16x8*)(a0l + (long)mt * 16 * K + s * 32);
            acc[mt] = __builtin_amdgcn_mfma_f32_16x16x32_bf16(ah, bhi, acc[mt], 0, 0, 0);
            acc[mt] = __builtin_amdgcn_mfma_f32_16x16x32_bf16(ah, blo, acc[mt], 0, 0, 0);
            acc[mt] = __builtin_amdgcn_mfma_f32_16x16x32_bf16(al, bhi, acc[mt], 0, 0, 0);
        }
        long inc = (s & 1) ? incB : incA;
        phi += inc; plo += inc;
    }

    if (OUTSPLIT) {
        #pragma unroll
        for (int mt = 0; mt < MTW; ++mt)
            #pragma unroll
            for (int r = 0; r < 4; ++r) {
                int co = co0 + mt * 16 + quad * 4 + r;
                float v = fmaxf(acc[mt][r], 0.0f);
                unsigned short h, l;
                split_bf16(v, h, l);
                long o = (((long)(b * COUT + co) * OPD + od + po) * OPD + oh + po) * OPRX
                       + ow + po;
                yhi[o] = h; ylo[o] = l;
            }
    } else {
        #pragma unroll
        for (int mt = 0; mt < MTW; ++mt)
            #pragma unroll
            for (int r = 0; r < 4; ++r) {
                int co = co0 + mt * 16 + quad * 4 + r;
                long o = (long)ks * sstride
                       + (((long)(b * COUT + co) * OPD + od) * OPD + oh) * OPRX + ow;
                yf[o] = acc[mt][r];
            }
    }
}

__global__ __launch_bounds__(256)
void combine4_relu(const float* __restrict__ p, float* __restrict__ y, long N, long ss)
{
    long idx = (long)blockIdx.x * blockDim.x + threadIdx.x;
    if (idx >= N) return;
    float v = p[idx] + p[idx + ss] + p[idx + 2 * ss] + p[idx + 3 * ss];
    y[idx] = fmaxf(v, 0.0f);
}

// ---------------- 1x1 conv (fp32 exact) ----------------
__global__ __launch_bounds__(128)
void conv1x1_b(const float* __restrict__ x, const float* __restrict__ w,
               const float* __restrict__ bias, float* __restrict__ y)
{
    const int co = blockIdx.x & 255, b = blockIdx.x >> 8;
    const int s4 = (int)threadIdx.x * 4;
    const float* xb = x + (long)b * 256 * 512 + s4;
    const float* wr = w + (long)co * 256;      // uniform -> s_load
    float bv = bias[co];
    float4 acc = {bv, bv, bv, bv};
    for (int ci = 0; ci < 256; ++ci) {
        float wv = wr[ci];
        float4 xv = *(const float4*)(xb + (long)ci * 512);
        acc.x = fmaf(xv.x, wv, acc.x); acc.y = fmaf(xv.y, wv, acc.y);
        acc.z = fmaf(xv.z, wv, acc.z); acc.w = fmaf(xv.w, wv, acc.w);
    }
    *(float4*)(y + (long)(b * 256 + co) * 512 + s4) = acc;
}

// ---------------- VQ (fp32 exact; unchanged) ----------------
__global__ void codenorm_kernel(const float* __restrict__ cb, float* __restrict__ norms)
{
    int k = blockIdx.x;
    int lane = threadIdx.x;
    float s = 0.0f;
    const float* row = cb + (long)k * 256;
    for (int d = lane; d < 256; d += 64) { float v = row[d]; s = fmaf(v, v, s); }
    for (int off = 32; off > 0; off >>= 1) s += __shfl_down(s, off);
    if (lane == 0) norms[k] = s;
}

__global__ __launch_bounds__(256)
void vq_kernel(const float* __restrict__ lat, const float* __restrict__ cb,
               const float* __restrict__ norms, unsigned short* __restrict__ q,
               float* __restrict__ idx_out)
{
    __shared__ __align__(16) float row[256];
    __shared__ float s_best[256];
    __shared__ int   s_bidx[256];
    int r = blockIdx.x;
    int t = threadIdx.x;
    row[t] = lat[(long)r * 256 + t];
    __syncthreads();

    const float4* rowv = (const float4*)row;
    float latn = 0.0f;
    #pragma unroll 4
    for (int d = 0; d < 64; ++d) {
        float4 rv = rowv[d];
        latn = fmaf(rv.x, rv.x, latn); latn = fmaf(rv.y, rv.y, latn);
        latn = fmaf(rv.z, rv.z, latn); latn = fmaf(rv.w, rv.w, latn);
    }

    float best = FLT_MAX;
    int bidx = 0x7fffffff;
    for (int j = 0; j < 4; ++j) {
        int k = t + 256 * j;
        const float4* cr = (const float4*)(cb + (long)k * 256);
        float dot = 0.0f;
        #pragma unroll 4
        for (int d = 0; d < 64; ++d) {
            float4 c = cr[d]; float4 rv = rowv[d];
            dot = fmaf(rv.x, c.x, dot); dot = fmaf(rv.y, c.y, dot);
            dot = fmaf(rv.z, c.z, dot); dot = fmaf(rv.w, c.w, dot);
        }
        float sc = latn - 2.0f * dot + norms[k];
        if (sc < best || (sc == best && k < bidx)) { best = sc; bidx = k; }
    }
    s_best[t] = best; s_bidx[t] = bidx;
    __syncthreads();
    for (int off = 128; off > 0; off >>= 1) {
        if (t < off) {
            float o = s_best[t + off]; int oi = s_bidx[t + off];
            if (o < s_best[t] || (o == s_best[t] && oi < s_bidx[t])) {
                s_best[t] = o; s_bidx[t] = oi;
            }
        }
        __syncthreads();
    }
    int bk = s_bidx[0];
    int b = r >> 9, n = r & 511;
    int zz = n >> 6, yy = (n >> 3) & 7, xx = n & 7;
    q[(long)(b * 256 + t) * 1000 + ((long)(zz + 1) * 10 + (yy + 1)) * 10 + (xx + 1)]
        = f32_to_bf16(cb[(long)bk * 256 + t]);
    if (t == 0) idx_out[r] = (float)bk;
}

// ---------------- decoder: MFMA implicit-GEMM ConvTranspose ----------------
// xflip=0: B slot a <-> x offset (1-ax), kw=(1-px)+2*ax (old cube kernel).
// xflip=1: B slot a <-> x offset ax,     kw=(1-px)+2*(1-ax) (dword-pair kernel).
__global__ __launch_bounds__(256)
void prep_convt_w(const float* __restrict__ w, short* __restrict__ Ap,
                  int Cin, int Cout, int xflip)
{
    const int K = Cin * 8;
    long total = 8L * Cout * K;
    long idx = (long)blockIdx.x * blockDim.x + threadIdx.x;
    if (idx >= total) return;
    int k = (int)(idx % K);
    int co = (int)((idx / K) % Cout);
    int p = (int)(idx / ((long)K * Cout));
    int ci = k >> 3, a = k & 7;
    int az = (a >> 2) & 1, ay = (a >> 1) & 1, ax = a & 1;
    int pz = p >> 2, py = (p >> 1) & 1, px = p & 1;
    int axw = xflip ? (1 - ax) : ax;
    int kd = (1 - pz) + 2 * az, kh = (1 - py) + 2 * ay, kw = (1 - px) + 2 * axw;
    float v = w[((long)ci * Cout + co) * 64 + kd * 16 + kh * 4 + kw];
    Ap[idx] = (short)f32_to_bf16(v);
}

// Old cube-N layout (kept for dec1, DIN=8): nt-slab XCD swizzle + px inner.
// R18: explicit 2-stage pipeline with RAW u16 staging (pack deferred to MFMA
// phase) + sched_barrier fences so loads issue in batches and stay hoisted.
template <int CIN, int COUT, int DIN, int OPAD, typename OutT>
__global__ __launch_bounds__(256)
void convt_mfma(const unsigned short* __restrict__ Xp, const short* __restrict__ Ap,
                const float* __restrict__ bias, OutT* __restrict__ Y)
{
    constexpr int PD = DIN + 2;
    constexpr int PD3 = PD * PD * PD;
    constexpr int T = DIN >> 2;
    constexpr int NT = T * T * T;
    constexpr int SLAB = NT / 8;
    constexpr int OPD = 2 * DIN + 2 * OPAD;
    constexpr int K = CIN * 8;
    constexpr int MG = COUT >> 6;
    constexpr int nsteps = K >> 5;
    static_assert((nsteps & 1) == 0, "pipeline assumes even step count");

    int bx = blockIdx.x;
    const int xcd = bx & 7;
    int local = bx >> 3;
    const int px = local & 1; local >>= 1;
    const int mg = local % MG; local /= MG;
    const int ntin = local % SLAB;
    const int pzy = local / SLAB;            // 0..3
    const int pz = pzy >> 1, py = pzy & 1;
    const int p = pz * 4 + py * 2 + px;
    const int nt = xcd * SLAB + ntin;

    const int lane = threadIdx.x & 63, wave = threadIdx.x >> 6;
    const int n16 = lane & 15, quad = lane >> 4;

    const int tx = nt % T, ty = (nt / T) % T, tz = nt / (T * T);
    const int mz = tz * 4 + wave, my = ty * 4 + (n16 >> 2), mx = tx * 4 + (n16 & 3);
    const int sp = ((mz + pz) * PD + (my + py)) * PD + (mx + px);

    const unsigned short* xq = Xp + (long)quad * PD3 + sp;

    const int cobase = mg * 64;
    const short* ap0 = Ap + ((long)p * COUT + cobase + n16) * K + quad * 8;

    f32x4 acc[4];
    #pragma unroll
    for (int cb = 0; cb < 4; ++cb) {
        const float* bp = bias + cobase + cb * 16 + quad * 4;
        acc[cb][0] = bp[0]; acc[cb][1] = bp[1]; acc[cb][2] = bp[2]; acc[cb][3] = bp[3];
    }

    unsigned short xr0[8], xr1[8];
    bf16x8 a0[4], a1[4];

    auto loadS = [&](int s, unsigned short* xr, bf16x8* af) {
        const unsigned short* xs = xq + (long)s * 4 * PD3;
        // raw loads only -- no pack here, so nothing forces a waitcnt per load
        xr[0] = xs[(PD + 1) * PD + 1];
        xr[1] = xs[(PD + 1) * PD];
        xr[2] = xs[PD * PD + 1];
        xr[3] = xs[PD * PD];
        xr[4] = xs[PD + 1];
        xr[5] = xs[PD];
        xr[6] = xs[1];
        xr[7] = xs[0];
        #pragma unroll
        for (int cb = 0; cb < 4; ++cb)
            af[cb] = *(const bf16x8*)(ap0 + (long)cb * 16 * K + s * 32);
    };
    auto mmaS = [&](const unsigned short* xr, const bf16x8* af) {
        bf16x8 bf;
        #pragma unroll
        for (int k = 0; k < 8; ++k) bf[k] = (short)xr[k];
        #pragma unroll
        for (int cb = 0; cb < 4; ++cb)
            acc[cb] = __builtin_amdgcn_mfma_f32_16x16x32_bf16(af[cb], bf, acc[cb], 0, 0, 0);
    };

    loadS(0, xr0, a0);
    for (int s = 0; s < nsteps; s += 2) {
        loadS(s + 1, xr1, a1);                // next step's loads in flight
        __builtin_amdgcn_sched_barrier(0);
        mmaS(xr0, a0);
        __builtin_amdgcn_sched_barrier(0);
        if (s + 2 < nsteps) loadS(s + 2, xr0, a0);
        __builtin_amdgcn_sched_barrier(0);
        mmaS(xr1, a1);
        __builtin_amdgcn_sched_barrier(0);
    }

    const int opz = 2 * mz + pz + OPAD, opy = 2 * my + py + OPAD, opx = 2 * mx + px + OPAD;
    const long spo = ((long)opz * OPD + opy) * OPD + opx;
    #pragma unroll
    for (int cb = 0; cb < 4; ++cb) {
        #pragma unroll
        for (int r = 0; r < 4; ++r) {
            int co = cobase + cb * 16 + quad * 4 + r;
            float v = fmaxf(acc[cb][r], 0.0f);
            store_act(Y + (long)co * OPD * OPD * OPD + spo, v);
        }
    }
}

// Dword-pair B-gather (dec2/dec3), R18 pipeline:
//  - stage RAW u16x4 loads (shift/extract deferred to the MFMA phase)
//  - sched_barrier(0) fences pin the load-block / MFMA-block interleave
//  - launch_bounds(256,4): VGPR cap 128, room for 2 stages of loads in flight
template <int CIN, int COUT, int DIN, int OPAD, int MXP, int MYP, typename OutT>
__global__ __launch_bounds__(256, 4)
void convt_mfma_v2(const unsigned short* __restrict__ Xp, const short* __restrict__ Ap,
                   const float* __restrict__ bias, OutT* __restrict__ Y)
{
    constexpr int PD = DIN + 2;
    constexpr int PD3 = PD * PD * PD;
    constexpr int OPD = 2 * DIN + 2 * OPAD;
    constexpr int K = CIN * 8;
    constexpr int MG = COUT >> 6;
    constexpr int nsteps = K >> 5;           // even for all our layers
    static_assert((nsteps & 1) == 0, "pipeline assumes even step count");
    constexpr int MXT = DIN / (16 * MXP);
    constexpr int MYT = DIN / (4 * MYP);
    constexpr int MZS = DIN / 8;             // mz per XCD slab
    constexpr int TPE = MXP * MYP;           // tiles per wave (one of MXP/MYP is 1)

    int bx = blockIdx.x;
    const int xcd = bx & 7;
    int local = bx >> 3;
    const int px = local & 1; local >>= 1;
    const int py = local & 1; local >>= 1;
    const int mg = local % MG; local /= MG;
    const int mxt = local % MXT; local /= MXT;
    const int myt = local % MYT; local /= MYT;
    const int pz = local & 1; local >>= 1;
    const int mzin = local;                  // 0..MZS-1
    const int mz = xcd * MZS + mzin;
    const int p = pz * 4 + py * 2 + px;

    const int lane = threadIdx.x & 63, wave = threadIdx.x >> 6;
    const int n16 = lane & 15, quad = lane >> 4;

    const int mx0 = mxt * (16 * MXP) + n16;
    const int my0 = myt * (4 * MYP) + wave * MYP;
    const int baseX = mx0 & ~1;
    const int sh = 16 * ((n16 & 1) + px);    // 0, 16, or 32
    const long sp = ((long)(mz + pz) * PD + (my0 + py)) * PD + baseX;

    const unsigned short* xq = Xp + (long)quad * PD3 + sp;

    const int cobase = mg * 64;
    const short* ap0 = Ap + ((long)p * COUT + cobase + n16) * K + quad * 8;

    f32x4 acc[TPE][4];
    #pragma unroll
    for (int t = 0; t < TPE; ++t)
        #pragma unroll
        for (int cb = 0; cb < 4; ++cb) {
            const float* bp = bias + cobase + cb * 16 + quad * 4;
            acc[t][cb][0] = bp[0]; acc[t][cb][1] = bp[1];
            acc[t][cb][2] = bp[2]; acc[t][cb][3] = bp[3];
        }

    constexpr int rowoff[4] = { (PD + 1) * PD, PD * PD, PD, 0 };

    union Frag { unsigned u[4]; bf16x8 b; };

    u16x4u raw0[TPE][4], raw1[TPE][4];       // RAW staged loads, no consumers
    bf16x8 a0[4], a1[4];

    auto loadStep = [&](int s, u16x4u (*raw)[4], bf16x8* af) {
        const unsigned short* xs = xq + (long)s * 4 * PD3;
        #pragma unroll
        for (int t = 0; t < TPE; ++t) {
            const int toff = (MXP > 1) ? t * 16 : t * PD;
            #pragma unroll
            for (int j = 0; j < 4; ++j)
                raw[t][j] = *(const u16x4u*)(xs + toff + rowoff[j]);
        }
        #pragma unroll
        for (int cb = 0; cb < 4; ++cb)
            af[cb] = *(const bf16x8*)(ap0 + (long)cb * 16 * K + s * 32);
    };

    auto mmaStep = [&](u16x4u (*raw)[4], bf16x8* af) {
        #pragma unroll
        for (int t = 0; t < TPE; ++t) {
            Frag fr;
            #pragma unroll
            for (int j = 0; j < 4; ++j) {
                union { u16x4u v; unsigned long long u; } c;
                c.v = raw[t][j];
                fr.u[j] = (unsigned)(c.u >> sh);
            }
            #pragma unroll
            for (int cb = 0; cb < 4; ++cb)
                acc[t][cb] = __builtin_amdgcn_mfma_f32_16x16x32_bf16(af[cb], fr.b,
                                                                     acc[t][cb], 0, 0, 0);
        }
    };

    loadStep(0, raw0, a0);
    for (int s = 0; s < nsteps; s += 2) {
        loadStep(s + 1, raw1, a1);            // next step's 12 loads in flight
        __builtin_amdgcn_sched_barrier(0);
        mmaStep(raw0, a0);
        __builtin_amdgcn_sched_barrier(0);
        if (s + 2 < nsteps) loadStep(s + 2, raw0, a0);
        __builtin_amdgcn_sched_barrier(0);
        mmaStep(raw1, a1);
        __builtin_amdgcn_sched_barrier(0);
    }

    const int opz = 2 * mz + pz + OPAD;
    #pragma unroll
    for (int t = 0; t < TPE; ++t) {
        const int opx = 2 * (mx0 + ((MXP > 1) ? t * 16 : 0)) + px + OPAD;
        const int opy = 2 * (my0 + ((MYP > 1) ? t : 0)) + py + OPAD;
        const long spo = ((long)opz * OPD + opy) * OPD + opx;
        #pragma unroll
        for (int cb = 0; cb < 4; ++cb) {
            #pragma unroll
            for (int r = 0; r < 4; ++r) {
                int co = cobase + cb * 16 + quad * 4 + r;
                float v = fmaxf(acc[t][cb][r], 0.0f);
                store_act(Y + (long)co * OPD * OPD * OPD + spo, v);
            }
        }
    }
}

// ---------------- dec4 as MFMA GEMM: 4 oh rows per wave (unchanged) ---------
__global__ __launch_bounds__(256)
void prep_dec4A(const float* __restrict__ w, short* __restrict__ Aw)
{
    int idx = blockIdx.x * 256 + (int)threadIdx.x;    // 0..65535
    int m = idx >> 12, k = idx & 4095;
    float v = (m < 3) ? w[m * 4096 + k] : 0.0f;
    Aw[idx] = (short)f32_to_bf16(v);
}

__global__ __launch_bounds__(256)
void conv_dec4_mfma(const float* __restrict__ d3, const short* __restrict__ Aw,
                    const float* __restrict__ bias, float* __restrict__ y)
{
    constexpr int D = 64, Dout = 61;
    int bx = blockIdx.x;
    const int slab = bx & 7;
    const int i = bx >> 3;                 // 0..127
    const int od = slab * 8 + (i >> 4);
    const int oh0 = (i & 15) * 4;          // covers oh0..oh0+3 (guard < 61)
    if (od >= Dout) return;
    const int lane = (int)threadIdx.x & 63, wave = (int)threadIdx.x >> 6;
    const int n16 = lane & 15, quad = lane >> 4;
    const int ow = wave * 16 + n16;

    f32x4 acc[4];
    #pragma unroll
    for (int j = 0; j < 4; ++j)
        #pragma unroll
        for (int r = 0; r < 4; ++r) {
            int co = quad * 4 + r;
            acc[j][r] = (co < 3) ? bias[co] : 0.0f;
        }

    const short* ap = Aw + (long)n16 * 4096 + quad * 8;   // m = lane&15
    const int kd0 = quad >> 1;
    const int kh0 = (quad & 1) * 2;
    const float* basez = d3 + ((long)(od + kd0) * D) * D + ow;
    int yoff[5];
    #pragma unroll
    for (int r = 0; r < 5; ++r) yoff[r] = min(oh0 + kh0 + r, D - 1) * D;

    #pragma unroll 4
    for (int s = 0; s < 128; ++s) {
        const int ci = s >> 1;
        const float* plane = basez + ((long)ci * D + (s & 1) * 2) * D * D;
        unsigned p0[5], p1[5];
        #pragma unroll
        for (int r = 0; r < 5; ++r) {
            f32x4u v = *(const f32x4u*)(plane + yoff[r]);
            p0[r] = (__float_as_uint(v[0]) >> 16) | (__float_as_uint(v[1]) & 0xffff0000u);
            p1[r] = (__float_as_uint(v[2]) >> 16) | (__float_as_uint(v[3]) & 0xffff0000u);
        }
        bf16x8 af = *(const bf16x8*)(ap + s * 32);
        #pragma unroll
        for (int j = 0; j < 4; ++j) {
            union { unsigned u[4]; bf16x8 b; } fr;
            fr.u[0] = p0[j];     fr.u[1] = p1[j];
            fr.u[2] = p0[j + 1]; fr.u[3] = p1[j + 1];
            acc[j] = __builtin_amdgcn_mfma_f32_16x16x32_bf16(af, fr.b, acc[j], 0, 0, 0);
        }
    }

    if (ow < Dout && quad == 0) {
        #pragma unroll
        for (int j = 0; j < 4; ++j) {
            const int oh = oh0 + j;
            if (oh >= Dout) continue;
            #pragma unroll
            for (int r = 0; r < 3; ++r)
                y[((long)(r * Dout + od) * Dout + oh) * Dout + ow] = tanhf(acc[j][r]);
        }
    }
}

extern "C" void kernel_launch(void* const* d_in, const int* in_sizes, int n_in,
                              void* d_out, int out_size, void* d_ws, size_t ws_size,
                              hipStream_t stream)
{
    const float* x        = (const float*)d_in[0];
    const float* enc_w1   = (const float*)d_in[1];
    const float* enc_b1   = (const float*)d_in[2];
    const float* enc_w2   = (const float*)d_in[3];
    const float* enc_b2   = (const float*)d_in[4];
    const float* enc_w3   = (const float*)d_in[5];
    const float* enc_b3   = (const float*)d_in[6];
    const float* enc_w4   = (const float*)d_in[7];
    const float* enc_b4   = (const float*)d_in[8];
    const float* codebook = (const float*)d_in[9];
    const float* dec_w1   = (const float*)d_in[10];
    const float* dec_b1   = (const float*)d_in[11];
    const float* dec_w2   = (const float*)d_in[12];
    const float* dec_b2   = (const float*)d_in[13];
    const float* dec_w3   = (const float*)d_in[14];
    const float* dec_b3   = (const float*)d_in[15];
    const float* dec_w4   = (const float*)d_in[16];
    const float* dec_b4   = (const float*)d_in[17];

    float* out = (float*)d_out;
    float* idx_out = out + 2L * 3 * 61 * 61 * 61;

    // ---- workspace (byte offsets) ----
    char* wsb = (char*)d_ws;
    float*          cn   = (float*)wsb;                        //      4,096
    unsigned short* qp   = (unsigned short*)(wsb + 4096);      //  1,024,000
    short*          Ap1  = (short*)(wsb + 1028096);            //  8,388,608
    short*          Ap2  = (short*)(wsb + 9416704);            //  4,194,304
    short*          Ap3  = (short*)(wsb + 13611008);           //  1,048,576
    short*          Aw4  = (short*)(wsb + 14659584);           //    131,072
    short*          W1hi = (short*)(wsb + 14790656);           //     24,576
    short*          W1lo = (short*)(wsb + 14815232);           //     24,576
    short*          W2hi = (short*)(wsb + 14839808);           //  1,048,576
    short*          W2lo = (short*)(wsb + 15888384);           //  1,048,576
    short*          W3hi = (short*)(wsb + 16936960);           //  4,194,304
    short*          W3lo = (short*)(wsb + 21131264);           //  4,194,304
    char* arena = wsb + 25325568;
    // encoder phase:
    unsigned short* xphi = (unsigned short*)arena;                    // (2,3,66,66,68)
    unsigned short* xplo = (unsigned short*)(arena + 3554496);
    unsigned short* h1hi = (unsigned short*)(arena + 7108992);        // (2,64,34,34,36)
    unsigned short* h1lo = (unsigned short*)(arena + 17762688);
    unsigned short* h2hi = (unsigned short*)(arena + 28416384);       // (2,128,18,18,20)
    unsigned short* h2lo = (unsigned short*)(arena + 31734144);
    float*          pp3  = (float*)(arena + 35051904);                // 4x(2,256,8^3)
    float*          h3   = (float*)(arena + 39246208);                // (2,256,512)
    float*          lat  = (float*)(arena + 40294784);                // (2,256,512)
    // decoder phase (after VQ; overlaps encoder buffers):
    unsigned short* d1 = (unsigned short*)arena;                      // (256,18^3) bf16
    unsigned short* d2 = (unsigned short*)(arena + 2985984);          // (128,34^3) bf16
    float*          d3 = (float*)(arena + 13047808);                  // (64,64^3) fp32
    // arena peak 80.2 MB; total 105.5 MB (< 112.2 MB proven in R0)

    dim3 blk(256);
    auto nblk = [](long n) { return dim3((unsigned)((n + 255) / 256)); };

    // ---- weight prep ----
    prep_convt_w<<<nblk(8L * 256 * 2048), blk, 0, stream>>>(dec_w1, Ap1, 256, 256, 0);
    prep_convt_w<<<nblk(8L * 128 * 2048), blk, 0, stream>>>(dec_w2, Ap2, 256, 128, 1);
    prep_convt_w<<<nblk(8L * 64 * 1024), blk, 0, stream>>>(dec_w3, Ap3, 128, 64, 1);
    prep_dec4A<<<dim3(256), blk, 0, stream>>>(dec_w4, Aw4);
    prep_split_w<<<nblk(12288), blk, 0, stream>>>(enc_w1, W1hi, W1lo, 12288);
    prep_split_w<<<nblk(524288), blk, 0, stream>>>(enc_w2, W2hi, W2lo, 524288);
    prep_split_w<<<nblk(2097152), blk, 0, stream>>>(enc_w3, W3hi, W3lo, 2097152);

    // ---- encoder (MFMA, bf16-pair) ----
    pad_input_split<<<nblk(6L * 66 * 66 * 68), blk, 0, stream>>>(x, xphi, xplo);
    zero_halo_ps<<<nblk(128L * 34 * 34 * 36), blk, 0, stream>>>(h1hi, 128, 34, 36);
    zero_halo_ps<<<nblk(128L * 34 * 34 * 36), blk, 0, stream>>>(h1lo, 128, 34, 36);
    conv_s2_mfma<3, 64, 32, 66, 68, 4, 2, 0, 1, 1><<<dim3(1024), blk, 0, stream>>>(
        xphi, xplo, W1hi, W1lo, enc_b1, h1hi, h1lo, nullptr, 34, 36, 1, 0);
    zero_halo_ps<<<nblk(256L * 18 * 18 * 20), blk, 0, stream>>>(h2hi, 256, 18, 20);
    zero_halo_ps<<<nblk(256L * 18 * 18 * 20), blk, 0, stream>>>(h2lo, 256, 18, 20);
    conv_s2_mfma<64, 128, 16, 34, 36, 2, 1, 0, 1, 1><<<dim3(512), blk, 0, stream>>>(
        h1hi, h1lo, W2hi, W2lo, enc_b2, h2hi, h2lo, nullptr, 18, 20, 1, 0);
    conv_s2_mfma<128, 256, 8, 18, 20, 4, 1, 1, 4, 0><<<dim3(256), blk, 0, stream>>>(
        h2hi, h2lo, W3hi, W3lo, enc_b3, nullptr, nullptr, pp3, 8, 8, 0, 262144);
    combine4_relu<<<nblk(262144), blk, 0, stream>>>(pp3, h3, 262144, 262144);
    conv1x1_b<<<dim3(512), dim3(128), 0, stream>>>(h3, enc_w4, enc_b4, lat);

    // ---- VQ (fp32 exact) ----
    codenorm_kernel<<<dim3(1024), dim3(64), 0, stream>>>(codebook, cn);
    zero_halo_t<unsigned short><<<nblk(512L * 10 * 10 * 10), blk, 0, stream>>>(qp, 512, 10);
    vq_kernel<<<dim3(1024), blk, 0, stream>>>(lat, codebook, cn, qp, idx_out);

    // ---- decoder halos ----
    zero_halo_t<unsigned short><<<nblk(256L * 18 * 18 * 18), blk, 0, stream>>>(d1, 256, 18);
    zero_halo_t<unsigned short><<<nblk(128L * 34 * 34 * 34), blk, 0, stream>>>(d2, 128, 34);

    // ---- decoder (MFMA) per batch ----
    for (int b = 0; b < 2; ++b) {
        const unsigned short* qb = qp + (long)b * 256 * 1000;
        float* outb = out + (long)b * 3 * 226981;
        // dec1 (DIN=8, old layout): grid = 8*2*4*1*4 = 256
        convt_mfma<256, 256, 8, 1, unsigned short><<<dim3(256), blk, 0, stream>>>(
            qb, Ap1, dec_b1, d1);
        // dec2 (v2, MXP=1 MYP=2): grid = 8 * (2*2*2*1*2*2*2) = 512
        convt_mfma_v2<256, 128, 16, 1, 1, 2, unsigned short><<<dim3(512), blk, 0, stream>>>(
            d1, Ap2, dec_b2, d2);
        // dec3 (v2, MXP=2 MYP=1): grid = 8 * (2*2*1*1*8*2*4) = 2048
        convt_mfma_v2<128, 64, 32, 0, 2, 1, float><<<dim3(2048), blk, 0, stream>>>(
            d2, Ap3, dec_b3, d3);
        conv_dec4_mfma<<<dim3(8 * 8 * 16), blk, 0, stream>>>(d3, Aw4, dec_b4, outb);
    }
}